// Round 9
// baseline (73.034 us; speedup 1.0000x reference)
//
#include <hip/hip_runtime.h>
#include <cstddef>

#define L1n 128
#define L2n 256
#define Kn  1024
#define KQ  256            // K per quarter
#define BK  64
#define NPH (KQ / BK)      // 4 phases

using frag_ab = __attribute__((ext_vector_type(8))) short;  // 8 bf16
using frag_cd = __attribute__((ext_vector_type(4))) float;  // 4 f32

// ws layout (floats)
#define P_OFF   0u                       // partials [b][q][256][128] : 8,388,608 floats (32 MB)
#define SSA_OFF 8388608u                 // [b][q][128] : 32768 floats
#define SSB_OFF 8421376u                 // [b][q][256] : 65536 floats
#define DST_OFF 8486912u                 // dist_t [b][col][row] : 2,097,152 floats (8 MB)

// RNE f32->bf16 pair pack (low, high)
__device__ __forceinline__ unsigned pack_bf16(float x, float y) {
    unsigned ux = __float_as_uint(x);
    ux = (ux + 0x7FFFu + ((ux >> 16) & 1u)) >> 16;
    unsigned uy = __float_as_uint(y);
    uy = (uy + 0x7FFFu + ((uy >> 16) & 1u)) & 0xFFFF0000u;
    return ux | uy;
}
__device__ __forceinline__ float dot4(float4 v) {
    return v.x * v.x + v.y * v.y + v.z * v.z + v.w * v.w;
}

// ---------------- Kernel 1: read-once K-split partial GEMM ----------------
// grid = 64 batches x 4 K-quarters = 256 blocks (1/CU, ALL CUs), 512 threads.
// Block computes the full 128x256 partial C^T for its K-quarter and the
// partial row sums-of-squares. Inputs are read EXACTLY ONCE chip-wide
// (100 MB) -- all 64x64-tile variants re-read 256 MB and pinned at 40us
// = 256MB / 6.4TB/s streaming BW. Operand-swapped MFMA -> coalesced
// transposed partial stores P[b][q][col][row].
__global__ __launch_bounds__(512) void gemm_part_kernel(
    const float* __restrict__ seq1,
    const float* __restrict__ seq2,
    float* __restrict__ ws)
{
    __shared__ __align__(16) unsigned char sA[2][128 * 128];  // 16 KB x2
    __shared__ __align__(16) unsigned char sB[2][256 * 128];  // 32 KB x2  (96 KB total)

    // bijective XCD-chunk swizzle (256 % 8 == 0): XCD x gets batches [8x,8x+8)
    const int wgid = ((blockIdx.x & 7) << 5) + (blockIdx.x >> 3);
    const int b    = wgid >> 2;
    const int q    = wgid & 3;        // K-quarter
    const int t    = threadIdx.x;
    const int lane = t & 63;
    const int w    = t >> 6;          // 0..7
    const int wr   = w >> 2;          // 0..1 : rows [wr*64,+64)
    const int wc   = w & 3;           // 0..3 : cols [wc*64,+64)

    // staging maps
    const int rA = t >> 2;            // 0..127, 4 threads/row
    const int jA = t & 3;
    const int rB = t >> 1;            // 0..255, 2 threads/row
    const int jB = t & 1;
    const int swzA = (rA & 7) << 4;
    const int swzB = (rB & 7) << 4;

    const float4* pA = reinterpret_cast<const float4*>(
        seq1 + (size_t)b * (L1n * Kn) + (size_t)rA * Kn + q * KQ) + jA * 4;
    const float4* pB = reinterpret_cast<const float4*>(
        seq2 + (size_t)b * (L2n * Kn) + (size_t)rB * Kn + q * KQ) + jB * 8;

    float ssA = 0.0f, ssB = 0.0f;
    frag_cd acc[4][4] = {};   // [ni][mi] operand-swapped: reg-dim = seq2 col

    float4 avs[4], bvs[8];

    auto issue = [&](int s) {
#pragma unroll
        for (int i = 0; i < 4; ++i) avs[i] = pA[s * 16 + i];
#pragma unroll
        for (int i = 0; i < 8; ++i) bvs[i] = pB[s * 16 + i];
    };
    auto convert = [&](int buf) {
#pragma unroll
        for (int i = 0; i < 4; ++i) {
            ssA += dot4(avs[i]);
            const int kb = (jA * 4 + i) * 8;
            *reinterpret_cast<uint2*>(&sA[buf][rA * 128 + (kb ^ swzA)]) =
                make_uint2(pack_bf16(avs[i].x, avs[i].y), pack_bf16(avs[i].z, avs[i].w));
        }
#pragma unroll
        for (int i = 0; i < 8; ++i) {
            ssB += dot4(bvs[i]);
            const int kb = (jB * 8 + i) * 8;
            *reinterpret_cast<uint2*>(&sB[buf][rB * 128 + (kb ^ swzB)]) =
                make_uint2(pack_bf16(bvs[i].x, bvs[i].y), pack_bf16(bvs[i].z, bvs[i].w));
        }
    };
    auto domfma = [&](int buf) {
#pragma unroll
        for (int kk = 0; kk < 2; ++kk) {
            const int kb = kk * 64 + ((lane >> 4) << 4);
            const int fswz = (lane & 7) << 4;
            frag_ab af[4], bf[4];
#pragma unroll
            for (int mi = 0; mi < 4; ++mi)
                af[mi] = *reinterpret_cast<const frag_ab*>(
                    &sA[buf][(wr * 64 + mi * 16 + (lane & 15)) * 128 + (kb ^ fswz)]);
#pragma unroll
            for (int ni = 0; ni < 4; ++ni)
                bf[ni] = *reinterpret_cast<const frag_ab*>(
                    &sB[buf][(wc * 64 + ni * 16 + (lane & 15)) * 128 + (kb ^ fswz)]);
#pragma unroll
            for (int ni = 0; ni < 4; ++ni)
#pragma unroll
                for (int mi = 0; mi < 4; ++mi)
                    acc[ni][mi] = __builtin_amdgcn_mfma_f32_16x16x32_bf16(
                        bf[ni], af[mi], acc[ni][mi], 0, 0, 0);
        }
    };

    issue(0);
    convert(0);

#pragma unroll
    for (int s = 0; s < NPH; ++s) {
        __syncthreads();
        if (s + 1 < NPH) issue(s + 1);     // in flight across barrier + MFMA
        domfma(s & 1);
        if (s + 1 < NPH) convert((s + 1) & 1);
    }

    // partial sums-of-squares -> ws (reduce over the staging partners, same wave)
    ssA += __shfl_xor(ssA, 1); ssA += __shfl_xor(ssA, 2);
    ssB += __shfl_xor(ssB, 1);
    if (jA == 0) ws[SSA_OFF + (size_t)(b * 4 + q) * 128 + rA] = ssA;
    if (jB == 0) ws[SSB_OFF + (size_t)(b * 4 + q) * 256 + rB] = ssB;

    // partial C^T store: P[b][q][n][m], lane&15 = m (coalesced)
    float* pbase = ws + P_OFF + (size_t)(b * 4 + q) * (L1n * L2n);
#pragma unroll
    for (int ni = 0; ni < 4; ++ni)
#pragma unroll
        for (int mi = 0; mi < 4; ++mi) {
            const int m_l = wr * 64 + mi * 16 + (lane & 15);
            const int n_b = wc * 64 + ni * 16 + ((lane >> 4) << 2);
#pragma unroll
            for (int reg = 0; reg < 4; ++reg)
                pbase[(size_t)(n_b + reg) * L1n + m_l] = acc[ni][mi][reg];
        }
}

// ---------------- Kernel 2: combine partials + norms -> transposed dist ----------------
// grid = 64 batches x 8 col-chunks = 512 blocks, 256 threads.
// dist_t[b][col][row] = 1 - (sum_q P[b][q][col][row]) * invA[row] * invB[col]
__global__ __launch_bounds__(256) void reduce_kernel(float* __restrict__ ws)
{
    __shared__ float sIA[128];
    __shared__ float sIB[32];
    const int blk = blockIdx.x;
    const int b   = blk >> 3;
    const int c0  = (blk & 7) * 32;
    const int t   = threadIdx.x;

    if (t < 128) {
        float s = 0.0f;
#pragma unroll
        for (int q = 0; q < 4; ++q) s += ws[SSA_OFF + (size_t)(b * 4 + q) * 128 + t];
        sIA[t] = rsqrtf(s);
    } else if (t < 160) {
        const int c = c0 + t - 128;
        float s = 0.0f;
#pragma unroll
        for (int q = 0; q < 4; ++q) s += ws[SSB_OFF + (size_t)(b * 4 + q) * 256 + c];
        sIB[t - 128] = rsqrtf(s);
    }
    __syncthreads();

    const int col = c0 + (t >> 3);
    const int r0  = (t & 7) * 16;
    const float ib = sIB[t >> 3];
    const float4* p0 = reinterpret_cast<const float4*>(
        ws + P_OFF + (size_t)(b * 4) * (L1n * L2n) + (size_t)col * L1n + r0);
    float4* dout = reinterpret_cast<float4*>(
        ws + DST_OFF + (size_t)b * (L1n * L2n) + (size_t)col * L1n + r0);

#pragma unroll
    for (int i = 0; i < 4; ++i) {
        const float4 s0 = p0[i];
        const float4 s1 = p0[8192 + i];      // q-stride = 128*256 floats = 8192 float4
        const float4 s2 = p0[16384 + i];
        const float4 s3 = p0[24576 + i];
        float4 o;
        o.x = 1.0f - (s0.x + s1.x + s2.x + s3.x) * sIA[r0 + 4 * i + 0] * ib;
        o.y = 1.0f - (s0.y + s1.y + s2.y + s3.y) * sIA[r0 + 4 * i + 1] * ib;
        o.z = 1.0f - (s0.z + s1.z + s2.z + s3.z) * sIA[r0 + 4 * i + 2] * ib;
        o.w = 1.0f - (s0.w + s1.w + s2.w + s3.w) * sIA[r0 + 4 * i + 3] * ib;
        dout[i] = o;
    }
}

// ---------------- Kernel 3: DTW lag-skewed column sweep, global-direct ----------------
// R4-proven (~2.4us): transposed dist_t[b][col][row], lane l owns rows 2l,2l+1,
// LAG=4 skew puts the shfl off the critical path; 16-deep float2 prefetch.
__global__ __launch_bounds__(64) void dtw_kernel(
    const float* __restrict__ dist, float* __restrict__ out)
{
    const int b    = blockIdx.x;
    const int lane = threadIdx.x;
    const float INF = 3.0e38f;
    const bool lane0 = (lane == 0);
    const float* base = dist + (size_t)b * (L1n * L2n) + 2 * lane;  // [col][row]

    float c0 = INF, c1 = INF;
    float sh0 = INF, sh1 = INF, sh2 = INF, sh3 = INF, sh4 = INF;

    auto ldval = [&](int tt) -> float2 {
        int jj = tt - 4 * lane;
        jj = jj < 0 ? 0 : (jj > L2n - 1 ? L2n - 1 : jj);
        return *reinterpret_cast<const float2*>(base + (size_t)jj * L1n);
    };

    auto step = [&](float2 d, bool t0) {
        float u = lane0 ? (t0 ? 0.0f : INF) : sh3;   // D(r0-1, jj)
        float g = lane0 ? INF : sh4;                  // D(r0-1, jj-1)
        float ugm = fminf(u, g);
        float n0 = d.x + fminf(c0, ugm);
        float n1 = d.y + fminf(fminf(c1, c0), n0);
        float snew = __shfl_up(n1, 1);
        sh4 = sh3; sh3 = sh2; sh2 = sh1; sh1 = sh0; sh0 = snew;
        c0 = n0; c1 = n1;
    };

    float2 pfA[8], pfB[8];
#pragma unroll
    for (int u = 0; u < 8; ++u) pfA[u] = ldval(u);
#pragma unroll
    for (int u = 0; u < 8; ++u) pfB[u] = ldval(8 + u);

#pragma unroll
    for (int u = 0; u < 8; ++u) step(pfA[u], u == 0);
#pragma unroll
    for (int u = 0; u < 8; ++u) pfA[u] = ldval(16 + u);

    int t = 8;
    for (int i = 0; i < 31; ++i) {    // t = 8 .. 503
        float2 curB[8];
#pragma unroll
        for (int u = 0; u < 8; ++u) curB[u] = pfB[u];
#pragma unroll
        for (int u = 0; u < 8; ++u) pfB[u] = ldval(t + 16 + u);
#pragma unroll
        for (int u = 0; u < 8; ++u) step(curB[u], false);

        float2 curA[8];
#pragma unroll
        for (int u = 0; u < 8; ++u) curA[u] = pfA[u];
#pragma unroll
        for (int u = 0; u < 8; ++u) pfA[u] = ldval(t + 24 + u);
#pragma unroll
        for (int u = 0; u < 8; ++u) step(curA[u], false);
        t += 16;
    }

#pragma unroll
    for (int u = 0; u < 4; ++u) step(pfB[u], false);

    // lane 63 finished (127,255) at t=507 -> c1
    if (lane == 63)
        out[b] = 1.0f / (1.0f + c1 * (1.0f / (float)(L1n + L2n)));
}

extern "C" void kernel_launch(void* const* d_in, const int* in_sizes, int n_in,
                              void* d_out, int out_size, void* d_ws, size_t ws_size,
                              hipStream_t stream) {
    const float* seq1 = (const float*)d_in[0];   // 64*128*1024 f32
    const float* seq2 = (const float*)d_in[1];   // 64*256*1024 f32
    float* out = (float*)d_out;                  // 64 f32
    float* ws  = (float*)d_ws;                   // >= 44 MB used

    gemm_part_kernel<<<dim3(256), dim3(512), 0, stream>>>(seq1, seq2, ws);
    reduce_kernel<<<dim3(512), dim3(256), 0, stream>>>(ws);
    dtw_kernel<<<dim3(64), dim3(64), 0, stream>>>(ws + DST_OFF, out);
}

// Round 10
// 71.061 us; speedup vs baseline: 1.0278x; 1.0278x over previous
//
#include <hip/hip_runtime.h>
#include <cstddef>

#define L1n 128
#define L2n 256
#define Kn  1024
#define KH  512            // K per half
#define BK  64
#define NPH (KH / BK)      // 8 phases

using frag_ab = __attribute__((ext_vector_type(8))) short;  // 8 bf16
using frag_cd = __attribute__((ext_vector_type(4))) float;  // 4 f32

// ws layout (floats)
#define P_OFF   0u                 // partials [b][kh][256][128] : 4,194,304 floats (16 MB)
#define SSA_OFF 4194304u           // [b][kh][128]
#define SSB_OFF 4210688u           // [b][kh][256]
#define DST_OFF 4243456u           // dist_t [b][col][row] : 2,097,152 floats (8 MB)

// RNE f32->bf16 pair pack (low, high)
__device__ __forceinline__ unsigned pack_bf16(float x, float y) {
    unsigned ux = __float_as_uint(x);
    ux = (ux + 0x7FFFu + ((ux >> 16) & 1u)) >> 16;
    unsigned uy = __float_as_uint(y);
    uy = (uy + 0x7FFFu + ((uy >> 16) & 1u)) & 0xFFFF0000u;
    return ux | uy;
}
__device__ __forceinline__ float dot4(float4 v) {
    return v.x * v.x + v.y * v.y + v.z * v.z + v.w * v.w;
}

// ---------------- Kernel 1: 128x128-tile, 2-K-half partial GEMM ----------------
// grid = 64 batches x 2 n-halves x 2 K-halves = 256 blocks (1/CU, ALL CUs),
// 512 threads (8 waves, 2M x 4N; wave-tile 64x32). Demand = A x2 + B x1
// = 128 MB (R7's 64x64 re-read 256 MB and pinned at the ~25 GB/s/CU demand
// cap). Pipeline = R5-proven 2-deep register prefetch + 8 phases, which
// sustained the cap; R9's 4-phase full-drain structure did not (latency-
// pinned at 56us). Operand-swapped MFMA -> coalesced transposed partials.
__global__ __launch_bounds__(512) void gemm_part_kernel(
    const float* __restrict__ seq1,
    const float* __restrict__ seq2,
    float* __restrict__ ws)
{
    __shared__ __align__(16) unsigned char sA[2][128 * 128];  // 16 KB x2
    __shared__ __align__(16) unsigned char sB[2][128 * 128];  // 16 KB x2 (64 KB)

    // bijective XCD-chunk swizzle (256 % 8 == 0): the 2 nt-blocks sharing an
    // A-panel land on the same XCD (A re-read becomes an L2 hit)
    const int wgid = ((blockIdx.x & 7) << 5) + (blockIdx.x >> 3);
    const int b    = wgid >> 2;
    const int nt   = (wgid >> 1) & 1;  // C-col half: cols [nt*128, +128)
    const int kh   = wgid & 1;         // K half: [kh*512, +512)
    const int t    = threadIdx.x;
    const int lane = t & 63;
    const int w    = t >> 6;           // 0..7
    const int wr   = w >> 2;           // 0..1 : tile rows [wr*64, +64)
    const int wc   = w & 3;            // 0..3 : tile cols [wc*32, +32)

    const int r   = t >> 2;            // staging row 0..127 (A and B)
    const int j   = t & 3;             // staging chunk 0..3
    const int swz = (r & 7) << 4;

    const float4* pA = reinterpret_cast<const float4*>(
        seq1 + (size_t)b * (L1n * Kn) + (size_t)r * Kn + kh * KH) + j * 4;
    const float4* pB = reinterpret_cast<const float4*>(
        seq2 + (size_t)b * (L2n * Kn) + (size_t)(nt * 128 + r) * Kn + kh * KH) + j * 4;

    float ssA = 0.0f, ssB = 0.0f;
    frag_cd acc[2][4] = {};   // [ni][mi] operand-swapped: reg-dim = seq2 col

    float4 avA[4], bvA[4], avB[4], bvB[4];

    auto issue = [&](float4* av, float4* bv, int s) {
#pragma unroll
        for (int i = 0; i < 4; ++i) { av[i] = pA[s * 16 + i]; bv[i] = pB[s * 16 + i]; }
    };
    auto convert = [&](const float4* av, const float4* bv, int buf) {
#pragma unroll
        for (int i = 0; i < 4; ++i) {
            ssA += dot4(av[i]);
            ssB += dot4(bv[i]);
            const int kb = (j * 4 + i) * 8;
            *reinterpret_cast<uint2*>(&sA[buf][r * 128 + (kb ^ swz)]) =
                make_uint2(pack_bf16(av[i].x, av[i].y), pack_bf16(av[i].z, av[i].w));
            *reinterpret_cast<uint2*>(&sB[buf][r * 128 + (kb ^ swz)]) =
                make_uint2(pack_bf16(bv[i].x, bv[i].y), pack_bf16(bv[i].z, bv[i].w));
        }
    };
    auto domfma = [&](int buf) {
#pragma unroll
        for (int kk = 0; kk < 2; ++kk) {
            const int kb = kk * 64 + ((lane >> 4) << 4);
            const int fswz = (lane & 7) << 4;
            frag_ab af[4], bf[2];
#pragma unroll
            for (int mi = 0; mi < 4; ++mi)
                af[mi] = *reinterpret_cast<const frag_ab*>(
                    &sA[buf][(wr * 64 + mi * 16 + (lane & 15)) * 128 + (kb ^ fswz)]);
#pragma unroll
            for (int ni = 0; ni < 2; ++ni)
                bf[ni] = *reinterpret_cast<const frag_ab*>(
                    &sB[buf][(wc * 32 + ni * 16 + (lane & 15)) * 128 + (kb ^ fswz)]);
#pragma unroll
            for (int ni = 0; ni < 2; ++ni)
#pragma unroll
                for (int mi = 0; mi < 4; ++mi)
                    acc[ni][mi] = __builtin_amdgcn_mfma_f32_16x16x32_bf16(
                        bf[ni], af[mi], acc[ni][mi], 0, 0, 0);
        }
    };

    // prologue: phase 0 staged; phase 1 in flight (set A)
    issue(avA, bvA, 0);
    convert(avA, bvA, 0);
    issue(avA, bvA, 1);

#pragma unroll
    for (int s = 0; s < NPH; s += 2) {
        __syncthreads();
        if (s + 2 < NPH) issue(avB, bvB, s + 2);   // 2 phases of covering distance
        domfma(0);
        convert(avA, bvA, 1);                      // data s+1, loaded a full phase ago

        __syncthreads();
        if (s + 3 < NPH) issue(avA, bvA, s + 3);
        domfma(1);
        if (s + 2 < NPH) convert(avB, bvB, 0);     // data s+2
    }

    // partial sums-of-squares (4 staging threads/row, same wave)
    ssA += __shfl_xor(ssA, 1); ssA += __shfl_xor(ssA, 2);
    ssB += __shfl_xor(ssB, 1); ssB += __shfl_xor(ssB, 2);
    // both nt-blocks write identical ssA values: benign same-value race
    if (j == 0) {
        ws[SSA_OFF + (size_t)(b * 2 + kh) * 128 + r] = ssA;
        ws[SSB_OFF + (size_t)(b * 2 + kh) * 256 + nt * 128 + r] = ssB;
    }

    // partial C^T store: P[b][kh][n][m], lane&15 = m (coalesced)
    float* pbase = ws + P_OFF + (size_t)(b * 2 + kh) * (L1n * L2n);
#pragma unroll
    for (int ni = 0; ni < 2; ++ni)
#pragma unroll
        for (int mi = 0; mi < 4; ++mi) {
            const int m_l = wr * 64 + mi * 16 + (lane & 15);
            const int n_b = wc * 32 + ni * 16 + ((lane >> 4) << 2);
#pragma unroll
            for (int reg = 0; reg < 4; ++reg)
                pbase[(size_t)(nt * 128 + n_b + reg) * L1n + m_l] = acc[ni][mi][reg];
        }
}

// ---------------- Kernel 2: combine 2 partials + norms -> transposed dist ----------------
// grid = 64 batches x 8 col-chunks = 512 blocks, 256 threads.
__global__ __launch_bounds__(256) void reduce_kernel(float* __restrict__ ws)
{
    __shared__ float sIA[128];
    __shared__ float sIB[32];
    const int blk = blockIdx.x;
    const int b   = blk >> 3;
    const int c0  = (blk & 7) * 32;
    const int t   = threadIdx.x;

    if (t < 128) {
        sIA[t] = rsqrtf(ws[SSA_OFF + (size_t)(b * 2 + 0) * 128 + t] +
                        ws[SSA_OFF + (size_t)(b * 2 + 1) * 128 + t]);
    } else if (t < 160) {
        const int c = c0 + t - 128;
        sIB[t - 128] = rsqrtf(ws[SSB_OFF + (size_t)(b * 2 + 0) * 256 + c] +
                              ws[SSB_OFF + (size_t)(b * 2 + 1) * 256 + c]);
    }
    __syncthreads();

    const int col = c0 + (t >> 3);
    const int r0  = (t & 7) * 16;
    const float ib = sIB[t >> 3];
    const float4* p0 = reinterpret_cast<const float4*>(
        ws + P_OFF + (size_t)(b * 2) * (L1n * L2n) + (size_t)col * L1n + r0);
    float4* dout = reinterpret_cast<float4*>(
        ws + DST_OFF + (size_t)b * (L1n * L2n) + (size_t)col * L1n + r0);

#pragma unroll
    for (int i = 0; i < 4; ++i) {
        const float4 s0 = p0[i];
        const float4 s1 = p0[8192 + i];     // kh-stride = 128*256 floats = 8192 float4
        float4 o;
        o.x = 1.0f - (s0.x + s1.x) * sIA[r0 + 4 * i + 0] * ib;
        o.y = 1.0f - (s0.y + s1.y) * sIA[r0 + 4 * i + 1] * ib;
        o.z = 1.0f - (s0.z + s1.z) * sIA[r0 + 4 * i + 2] * ib;
        o.w = 1.0f - (s0.w + s1.w) * sIA[r0 + 4 * i + 3] * ib;
        dout[i] = o;
    }
}

// ---------------- Kernel 3: DTW lag-skewed column sweep, global-direct ----------------
// R4-proven (~2.4us): transposed dist_t[b][col][row], lane l owns rows 2l,2l+1,
// LAG=4 skew puts the shfl off the critical path; 16-deep float2 prefetch.
__global__ __launch_bounds__(64) void dtw_kernel(
    const float* __restrict__ dist, float* __restrict__ out)
{
    const int b    = blockIdx.x;
    const int lane = threadIdx.x;
    const float INF = 3.0e38f;
    const bool lane0 = (lane == 0);
    const float* base = dist + (size_t)b * (L1n * L2n) + 2 * lane;  // [col][row]

    float c0 = INF, c1 = INF;
    float sh0 = INF, sh1 = INF, sh2 = INF, sh3 = INF, sh4 = INF;

    auto ldval = [&](int tt) -> float2 {
        int jj = tt - 4 * lane;
        jj = jj < 0 ? 0 : (jj > L2n - 1 ? L2n - 1 : jj);
        return *reinterpret_cast<const float2*>(base + (size_t)jj * L1n);
    };

    auto step = [&](float2 d, bool t0) {
        float u = lane0 ? (t0 ? 0.0f : INF) : sh3;   // D(r0-1, jj)
        float g = lane0 ? INF : sh4;                  // D(r0-1, jj-1)
        float ugm = fminf(u, g);
        float n0 = d.x + fminf(c0, ugm);
        float n1 = d.y + fminf(fminf(c1, c0), n0);
        float snew = __shfl_up(n1, 1);
        sh4 = sh3; sh3 = sh2; sh2 = sh1; sh1 = sh0; sh0 = snew;
        c0 = n0; c1 = n1;
    };

    float2 pfA[8], pfB[8];
#pragma unroll
    for (int u = 0; u < 8; ++u) pfA[u] = ldval(u);
#pragma unroll
    for (int u = 0; u < 8; ++u) pfB[u] = ldval(8 + u);

#pragma unroll
    for (int u = 0; u < 8; ++u) step(pfA[u], u == 0);
#pragma unroll
    for (int u = 0; u < 8; ++u) pfA[u] = ldval(16 + u);

    int t = 8;
    for (int i = 0; i < 31; ++i) {    // t = 8 .. 503
        float2 curB[8];
#pragma unroll
        for (int u = 0; u < 8; ++u) curB[u] = pfB[u];
#pragma unroll
        for (int u = 0; u < 8; ++u) pfB[u] = ldval(t + 16 + u);
#pragma unroll
        for (int u = 0; u < 8; ++u) step(curB[u], false);

        float2 curA[8];
#pragma unroll
        for (int u = 0; u < 8; ++u) curA[u] = pfA[u];
#pragma unroll
        for (int u = 0; u < 8; ++u) pfA[u] = ldval(t + 24 + u);
#pragma unroll
        for (int u = 0; u < 8; ++u) step(curA[u], false);
        t += 16;
    }

#pragma unroll
    for (int u = 0; u < 4; ++u) step(pfB[u], false);

    // lane 63 finished (127,255) at t=507 -> c1
    if (lane == 63)
        out[b] = 1.0f / (1.0f + c1 * (1.0f / (float)(L1n + L2n)));
}

extern "C" void kernel_launch(void* const* d_in, const int* in_sizes, int n_in,
                              void* d_out, int out_size, void* d_ws, size_t ws_size,
                              hipStream_t stream) {
    const float* seq1 = (const float*)d_in[0];   // 64*128*1024 f32
    const float* seq2 = (const float*)d_in[1];   // 64*256*1024 f32
    float* out = (float*)d_out;                  // 64 f32
    float* ws  = (float*)d_ws;                   // ~25 MB used

    gemm_part_kernel<<<dim3(256), dim3(512), 0, stream>>>(seq1, seq2, ws);
    reduce_kernel<<<dim3(512), dim3(256), 0, stream>>>(ws);
    dtw_kernel<<<dim3(64), dim3(64), 0, stream>>>(ws + DST_OFF, out);
}

// Round 11
// 68.614 us; speedup vs baseline: 1.0644x; 1.0357x over previous
//
#include <hip/hip_runtime.h>
#include <cstddef>

#define L1n 128
#define L2n 256
#define Kn  1024

using frag_ab = __attribute__((ext_vector_type(8))) short;  // 8 bf16
using frag_cd = __attribute__((ext_vector_type(4))) float;  // 4 f32

// RNE f32->bf16 pair pack (low, high)
__device__ __forceinline__ unsigned pack_bf16(float x, float y) {
    unsigned ux = __float_as_uint(x);
    ux = (ux + 0x7FFFu + ((ux >> 16) & 1u)) >> 16;
    unsigned uy = __float_as_uint(y);
    uy = (uy + 0x7FFFu + ((uy >> 16) & 1u)) & 0xFFFF0000u;
    return ux | uy;
}
__device__ __forceinline__ float dot4(float4 v) {
    return v.x * v.x + v.y * v.y + v.z * v.z + v.w * v.w;
}
__device__ __forceinline__ frag_ab mk_frag(float4 a, float4 b) {
    union { frag_ab f; unsigned u[4]; } r;
    r.u[0] = pack_bf16(a.x, a.y);
    r.u[1] = pack_bf16(a.z, a.w);
    r.u[2] = pack_bf16(b.x, b.y);
    r.u[3] = pack_bf16(b.z, b.w);
    return r.f;
}

// ---------------- Kernel 1: barrier-free LDS-free per-wave GEMM + norms + dist ----------------
// 256 blocks x 128 threads (2 waves). Each WAVE owns a 64x64 output tile x
// full K=1024: MFMA fragments loaded straight from global f32 (2 float4/lane
// per fragment), converted to bf16 in registers, operand-swapped MFMA.
// NO __syncthreads, NO LDS: each wave self-paces with a double-buffered
// fragment set, so loads stay in flight continuously (the dtw kernel proved
// 52 GB/s/CU this way; barrier-phased GEMMs drain vmcnt(0) every phase and
// cap at ~25). Norms per-wave in-register (shfl reduce) -> no norm traffic,
// no partials, no reduce kernel. XCD swizzle: a batch's 4 blocks share an XCD
// so the A x4 / B x2 re-reads are L2 hits.
__global__ __launch_bounds__(128) void gemm_dist_kernel(
    const float* __restrict__ seq1,
    const float* __restrict__ seq2,
    float* __restrict__ dist)
{
    // bijective XCD-chunk swizzle (256 % 8 == 0)
    const int wgid = ((blockIdx.x & 7) << 5) + (blockIdx.x >> 3);
    const int b    = wgid >> 2;          // batch
    const int nt   = wgid & 3;           // col-quarter [nt*64, +64)
    const int mt   = threadIdx.x >> 6;   // wave id = row-half [mt*64, +64)
    const int lane = threadIdx.x & 63;
    const int lr   = lane & 15;          // fragment row
    const int lk   = (lane >> 4) << 3;   // fragment k-offset (elements)

    const float* Ab = seq1 + (size_t)b * (L1n * Kn) + (size_t)(mt * 64) * Kn;
    const float* Bb = seq2 + (size_t)b * (L2n * Kn) + (size_t)(nt * 64) * Kn;

    const float4* pa[4];
    const float4* pb[4];
#pragma unroll
    for (int i = 0; i < 4; ++i) {
        pa[i] = reinterpret_cast<const float4*>(Ab + (size_t)(i * 16 + lr) * Kn + lk);
        pb[i] = reinterpret_cast<const float4*>(Bb + (size_t)(i * 16 + lr) * Kn + lk);
    }

    frag_cd acc[4][4] = {};              // [ni][mi], reg-dim = seq2 col
    float ssA[4] = {}, ssB[4] = {};

    // two named fragment sets (static indexing only)
    float4 a0[4][2], b0[4][2], a1[4][2], b1[4][2];

#define LOAD(AS, BS, ks)                                   \
    {                                                      \
        const int _o = (ks) * 8;                           \
        _Pragma("unroll")                                  \
        for (int i = 0; i < 4; ++i) {                      \
            AS[i][0] = pa[i][_o]; AS[i][1] = pa[i][_o + 1];\
            BS[i][0] = pb[i][_o]; BS[i][1] = pb[i][_o + 1];\
        }                                                  \
    }

#define PROC(AS, BS)                                               \
    {                                                              \
        frag_ab af[4], bf[4];                                      \
        _Pragma("unroll")                                          \
        for (int i = 0; i < 4; ++i) {                              \
            ssA[i] += dot4(AS[i][0]) + dot4(AS[i][1]);             \
            ssB[i] += dot4(BS[i][0]) + dot4(BS[i][1]);             \
            af[i] = mk_frag(AS[i][0], AS[i][1]);                   \
            bf[i] = mk_frag(BS[i][0], BS[i][1]);                   \
        }                                                          \
        _Pragma("unroll")                                          \
        for (int ni = 0; ni < 4; ++ni)                             \
            _Pragma("unroll")                                      \
            for (int mi = 0; mi < 4; ++mi)                         \
                acc[ni][mi] = __builtin_amdgcn_mfma_f32_16x16x32_bf16( \
                    bf[ni], af[mi], acc[ni][mi], 0, 0, 0);         \
    }

    LOAD(a0, b0, 0);
    for (int ks = 0; ks < 32; ks += 2) {
        if (ks + 1 < 32) LOAD(a1, b1, ks + 1);
        PROC(a0, b0);
        if (ks + 2 < 32) LOAD(a0, b0, ks + 2);
        PROC(a1, b1);
    }
#undef LOAD
#undef PROC

    // row/col sums of squares: lanes lr, lr+16, lr+32, lr+48 cover one row
#pragma unroll
    for (int i = 0; i < 4; ++i) {
        ssA[i] += __shfl_xor(ssA[i], 16); ssA[i] += __shfl_xor(ssA[i], 32);
        ssB[i] += __shfl_xor(ssB[i], 16); ssB[i] += __shfl_xor(ssB[i], 32);
    }
    float iA[4], iB[4];
#pragma unroll
    for (int i = 0; i < 4; ++i) { iA[i] = rsqrtf(ssA[i]); iB[i] = rsqrtf(ssB[i]); }

    // epilogue: dist_t[b][col][row] = 1 - acc*invA*invB (coalesced: lr = row)
    float* dT = dist + (size_t)b * (L1n * L2n);
    const int csub = (lane >> 4) << 2;
#pragma unroll
    for (int ni = 0; ni < 4; ++ni) {
        float ib0 = __shfl(iB[ni], csub + 0);
        float ib1 = __shfl(iB[ni], csub + 1);
        float ib2 = __shfl(iB[ni], csub + 2);
        float ib3 = __shfl(iB[ni], csub + 3);
#pragma unroll
        for (int mi = 0; mi < 4; ++mi) {
            const int row = mt * 64 + mi * 16 + lr;
            const int col = nt * 64 + ni * 16 + csub;
            const float ia = iA[mi];
            dT[(size_t)(col + 0) * L1n + row] = 1.0f - acc[ni][mi][0] * ia * ib0;
            dT[(size_t)(col + 1) * L1n + row] = 1.0f - acc[ni][mi][1] * ia * ib1;
            dT[(size_t)(col + 2) * L1n + row] = 1.0f - acc[ni][mi][2] * ia * ib2;
            dT[(size_t)(col + 3) * L1n + row] = 1.0f - acc[ni][mi][3] * ia * ib3;
        }
    }
}

// ---------------- Kernel 2: DTW lag-skewed column sweep, global-direct ----------------
// R4-proven (~2.4us): transposed dist_t[b][col][row], lane l owns rows 2l,2l+1,
// LAG=4 skew puts the shfl off the critical path; 16-deep float2 prefetch.
__global__ __launch_bounds__(64) void dtw_kernel(
    const float* __restrict__ dist, float* __restrict__ out)
{
    const int b    = blockIdx.x;
    const int lane = threadIdx.x;
    const float INF = 3.0e38f;
    const bool lane0 = (lane == 0);
    const float* base = dist + (size_t)b * (L1n * L2n) + 2 * lane;  // [col][row]

    float c0 = INF, c1 = INF;
    float sh0 = INF, sh1 = INF, sh2 = INF, sh3 = INF, sh4 = INF;

    auto ldval = [&](int tt) -> float2 {
        int jj = tt - 4 * lane;
        jj = jj < 0 ? 0 : (jj > L2n - 1 ? L2n - 1 : jj);
        return *reinterpret_cast<const float2*>(base + (size_t)jj * L1n);
    };

    auto step = [&](float2 d, bool t0) {
        float u = lane0 ? (t0 ? 0.0f : INF) : sh3;   // D(r0-1, jj)
        float g = lane0 ? INF : sh4;                  // D(r0-1, jj-1)
        float ugm = fminf(u, g);
        float n0 = d.x + fminf(c0, ugm);
        float n1 = d.y + fminf(fminf(c1, c0), n0);
        float snew = __shfl_up(n1, 1);
        sh4 = sh3; sh3 = sh2; sh2 = sh1; sh1 = sh0; sh0 = snew;
        c0 = n0; c1 = n1;
    };

    float2 pfA[8], pfB[8];
#pragma unroll
    for (int u = 0; u < 8; ++u) pfA[u] = ldval(u);
#pragma unroll
    for (int u = 0; u < 8; ++u) pfB[u] = ldval(8 + u);

#pragma unroll
    for (int u = 0; u < 8; ++u) step(pfA[u], u == 0);
#pragma unroll
    for (int u = 0; u < 8; ++u) pfA[u] = ldval(16 + u);

    int t = 8;
    for (int i = 0; i < 31; ++i) {    // t = 8 .. 503
        float2 curB[8];
#pragma unroll
        for (int u = 0; u < 8; ++u) curB[u] = pfB[u];
#pragma unroll
        for (int u = 0; u < 8; ++u) pfB[u] = ldval(t + 16 + u);
#pragma unroll
        for (int u = 0; u < 8; ++u) step(curB[u], false);

        float2 curA[8];
#pragma unroll
        for (int u = 0; u < 8; ++u) curA[u] = pfA[u];
#pragma unroll
        for (int u = 0; u < 8; ++u) pfA[u] = ldval(t + 24 + u);
#pragma unroll
        for (int u = 0; u < 8; ++u) step(curA[u], false);
        t += 16;
    }

#pragma unroll
    for (int u = 0; u < 4; ++u) step(pfB[u], false);

    // lane 63 finished (127,255) at t=507 -> c1
    if (lane == 63)
        out[b] = 1.0f / (1.0f + c1 * (1.0f / (float)(L1n + L2n)));
}

extern "C" void kernel_launch(void* const* d_in, const int* in_sizes, int n_in,
                              void* d_out, int out_size, void* d_ws, size_t ws_size,
                              hipStream_t stream) {
    const float* seq1 = (const float*)d_in[0];   // 64*128*1024 f32
    const float* seq2 = (const float*)d_in[1];   // 64*256*1024 f32
    float* out  = (float*)d_out;                 // 64 f32
    float* dist = (float*)d_ws;                  // 8 MB scratch (transposed dist)

    gemm_dist_kernel<<<dim3(256), dim3(128), 0, stream>>>(seq1, seq2, dist);
    dtw_kernel<<<dim3(64), dim3(64), 0, stream>>>(dist, out);
}

// Round 12
// 51.207 us; speedup vs baseline: 1.4262x; 1.3399x over previous
//
#include <hip/hip_runtime.h>
#include <cstddef>

#define L1n 128
#define L2n 256
#define Kn  1024

using frag_ab = __attribute__((ext_vector_type(8))) short;  // 8 bf16
using frag_cd = __attribute__((ext_vector_type(4))) float;  // 4 f32

// RNE f32->bf16 pair pack (low, high)
__device__ __forceinline__ unsigned pack_bf16(float x, float y) {
    unsigned ux = __float_as_uint(x);
    ux = (ux + 0x7FFFu + ((ux >> 16) & 1u)) >> 16;
    unsigned uy = __float_as_uint(y);
    uy = (uy + 0x7FFFu + ((uy >> 16) & 1u)) & 0xFFFF0000u;
    return ux | uy;
}

// Raw barrier WITHOUT vmcnt drain: ds-visibility only. __syncthreads() would
// emit s_waitcnt vmcnt(0) and kill the cross-phase global-load pipeline
// (T3/T4 mechanism; learn_hip m218: counted-vs-drain0 = +38-73%).
#define PHASE_BARRIER() do {                                   \
    asm volatile("s_waitcnt lgkmcnt(0)" ::: "memory");         \
    __builtin_amdgcn_s_barrier();                              \
    __builtin_amdgcn_sched_barrier(0);                         \
} while (0)

// ---------------- Kernel 1: fused row-norm + bf16-MFMA GEMM + dist ----------------
// R5 structure byte-for-byte (512 blocks x 256 thr, 64x64 tile, BK=64,
// 2-deep reg prefetch, swizzled LDS, operand-swapped MFMA -> coalesced
// transposed stores) with ONE change: in-loop __syncthreads() replaced by
// lgkmcnt(0)+raw s_barrier, so prefetched global loads stay in flight
// across phase barriers. + T5 setprio around the MFMA cluster.
__global__ __launch_bounds__(256) void gemm_dist_kernel(
    const float* __restrict__ seq1,
    const float* __restrict__ seq2,
    float* __restrict__ dist)
{
    __shared__ __align__(16) unsigned char sA[2][8192];  // 64 rows x 128 B
    __shared__ __align__(16) unsigned char sB[2][8192];
    __shared__ float sInvA[64];
    __shared__ float sInvB[64];

    // bijective XCD-chunk swizzle (512 % 8 == 0)
    const int wg   = ((blockIdx.x & 7) << 6) + (blockIdx.x >> 3);
    const int b    = wg >> 3;
    const int mt   = (wg >> 2) & 1;
    const int nt   = wg & 3;
    const int t    = threadIdx.x;
    const int lane = t & 63;
    const int w    = t >> 6;
    const int wr   = w >> 1;
    const int wc   = w & 1;
    const int r    = t >> 2;     // staging row 0..63
    const int j    = t & 3;      // staging chunk 0..3
    const int swz  = (r & 7) << 4;

    const float4* pA = reinterpret_cast<const float4*>(
        seq1 + (size_t)b * (L1n * Kn) + (size_t)(mt * 64 + r) * Kn) + j;
    const float4* pB = reinterpret_cast<const float4*>(
        seq2 + (size_t)b * (L2n * Kn) + (size_t)(nt * 64 + r) * Kn) + j;

    float ssA = 0.0f, ssB = 0.0f;
    frag_cd acc[2][2] = {};   // [nj][mi] (operand-swapped)

    float4 avA[4], bvA[4], avB[4], bvB[4];

    auto issue = [&](float4* av, float4* bv, int s) {
#pragma unroll
        for (int i = 0; i < 4; ++i) { av[i] = pA[s * 16 + 4 * i]; bv[i] = pB[s * 16 + 4 * i]; }
    };
    auto convert = [&](const float4* av, const float4* bv, int buf) {
#pragma unroll
        for (int i = 0; i < 4; ++i) {
            ssA += av[i].x * av[i].x + av[i].y * av[i].y + av[i].z * av[i].z + av[i].w * av[i].w;
            ssB += bv[i].x * bv[i].x + bv[i].y * bv[i].y + bv[i].z * bv[i].z + bv[i].w * bv[i].w;
            const int kb = (j + 4 * i) * 8;
            *reinterpret_cast<uint2*>(&sA[buf][r * 128 + (kb ^ swz)]) =
                make_uint2(pack_bf16(av[i].x, av[i].y), pack_bf16(av[i].z, av[i].w));
            *reinterpret_cast<uint2*>(&sB[buf][r * 128 + (kb ^ swz)]) =
                make_uint2(pack_bf16(bv[i].x, bv[i].y), pack_bf16(bv[i].z, bv[i].w));
        }
    };
    auto domfma = [&](int buf) {
        __builtin_amdgcn_s_setprio(1);
#pragma unroll
        for (int kk = 0; kk < 2; ++kk) {
            const int kb = kk * 64 + ((lane >> 4) << 4);
            const int m0 = wr * 32 + (lane & 15);
            const int n0 = wc * 32 + (lane & 15);
            const int fswz = (lane & 7) << 4;
            frag_ab a0 = *reinterpret_cast<const frag_ab*>(&sA[buf][m0 * 128 + (kb ^ fswz)]);
            frag_ab a1 = *reinterpret_cast<const frag_ab*>(&sA[buf][(m0 + 16) * 128 + (kb ^ fswz)]);
            frag_ab b0 = *reinterpret_cast<const frag_ab*>(&sB[buf][n0 * 128 + (kb ^ fswz)]);
            frag_ab b1 = *reinterpret_cast<const frag_ab*>(&sB[buf][(n0 + 16) * 128 + (kb ^ fswz)]);
            // swapped: reg-dim = seq2 col, lane&15 = seq1 row
            acc[0][0] = __builtin_amdgcn_mfma_f32_16x16x32_bf16(b0, a0, acc[0][0], 0, 0, 0);
            acc[0][1] = __builtin_amdgcn_mfma_f32_16x16x32_bf16(b0, a1, acc[0][1], 0, 0, 0);
            acc[1][0] = __builtin_amdgcn_mfma_f32_16x16x32_bf16(b1, a0, acc[1][0], 0, 0, 0);
            acc[1][1] = __builtin_amdgcn_mfma_f32_16x16x32_bf16(b1, a1, acc[1][1], 0, 0, 0);
        }
        __builtin_amdgcn_s_setprio(0);
    };

    // prologue: step 0 -> buf0; step 1 pending in avA
    issue(avA, bvA, 0);
    convert(avA, bvA, 0);
    issue(avA, bvA, 1);

#pragma unroll
    for (int s = 0; s < 16; s += 2) {
        PHASE_BARRIER();
        if (s + 2 < 16) issue(avB, bvB, s + 2);   // stays in flight across barriers
        domfma(0);
        convert(avA, bvA, 1);                      // data s+1 (loaded a full phase ago)

        PHASE_BARRIER();
        if (s + 3 < 16) issue(avA, bvA, s + 3);
        domfma(1);
        if (s + 2 < 16) convert(avB, bvB, 0);      // data s+2
    }

    // full-row sum of squares: threads 4r..4r+3 share row r (same wave)
    ssA += __shfl_xor(ssA, 1); ssA += __shfl_xor(ssA, 2);
    ssB += __shfl_xor(ssB, 1); ssB += __shfl_xor(ssB, 2);
    if (j == 0) { sInvA[r] = rsqrtf(ssA); sInvB[r] = rsqrtf(ssB); }
    __syncthreads();   // epilogue: full sync is fine (one-time)

    // epilogue: dist_t[b][col][row] = 1 - acc^T * invA * invB, coalesced stores
    float* dbase = dist + (size_t)b * (L1n * L2n);
#pragma unroll
    for (int nj = 0; nj < 2; ++nj)
#pragma unroll
        for (int mi = 0; mi < 2; ++mi) {
            const int m_l = wr * 32 + mi * 16 + (lane & 15);
            const int n_b = wc * 32 + nj * 16 + ((lane >> 4) << 2);
            const float ia = sInvA[m_l];
            const int grow = mt * 64 + m_l;
#pragma unroll
            for (int reg = 0; reg < 4; ++reg) {
                const int n_l = n_b + reg;
                dbase[(size_t)(nt * 64 + n_l) * L1n + grow] =
                    1.0f - acc[nj][mi][reg] * ia * sInvB[n_l];
            }
        }
}

// ---------------- Kernel 2: DTW lag-skewed column sweep, global-direct ----------------
// R4-proven (~2.4us): transposed dist_t[b][col][row], lane l owns rows 2l,2l+1,
// LAG=4 skew puts the shfl off the critical path; 16-deep float2 prefetch.
__global__ __launch_bounds__(64) void dtw_kernel(
    const float* __restrict__ dist, float* __restrict__ out)
{
    const int b    = blockIdx.x;
    const int lane = threadIdx.x;
    const float INF = 3.0e38f;
    const bool lane0 = (lane == 0);
    const float* base = dist + (size_t)b * (L1n * L2n) + 2 * lane;  // [col][row]

    float c0 = INF, c1 = INF;
    float sh0 = INF, sh1 = INF, sh2 = INF, sh3 = INF, sh4 = INF;

    auto ldval = [&](int tt) -> float2 {
        int jj = tt - 4 * lane;
        jj = jj < 0 ? 0 : (jj > L2n - 1 ? L2n - 1 : jj);
        return *reinterpret_cast<const float2*>(base + (size_t)jj * L1n);
    };

    auto step = [&](float2 d, bool t0) {
        float u = lane0 ? (t0 ? 0.0f : INF) : sh3;   // D(r0-1, jj)
        float g = lane0 ? INF : sh4;                  // D(r0-1, jj-1)
        float ugm = fminf(u, g);
        float n0 = d.x + fminf(c0, ugm);
        float n1 = d.y + fminf(fminf(c1, c0), n0);
        float snew = __shfl_up(n1, 1);
        sh4 = sh3; sh3 = sh2; sh2 = sh1; sh1 = sh0; sh0 = snew;
        c0 = n0; c1 = n1;
    };

    float2 pfA[8], pfB[8];
#pragma unroll
    for (int u = 0; u < 8; ++u) pfA[u] = ldval(u);
#pragma unroll
    for (int u = 0; u < 8; ++u) pfB[u] = ldval(8 + u);

#pragma unroll
    for (int u = 0; u < 8; ++u) step(pfA[u], u == 0);
#pragma unroll
    for (int u = 0; u < 8; ++u) pfA[u] = ldval(16 + u);

    int t = 8;
    for (int i = 0; i < 31; ++i) {    // t = 8 .. 503
        float2 curB[8];
#pragma unroll
        for (int u = 0; u < 8; ++u) curB[u] = pfB[u];
#pragma unroll
        for (int u = 0; u < 8; ++u) pfB[u] = ldval(t + 16 + u);
#pragma unroll
        for (int u = 0; u < 8; ++u) step(curB[u], false);

        float2 curA[8];
#pragma unroll
        for (int u = 0; u < 8; ++u) curA[u] = pfA[u];
#pragma unroll
        for (int u = 0; u < 8; ++u) pfA[u] = ldval(t + 24 + u);
#pragma unroll
        for (int u = 0; u < 8; ++u) step(curA[u], false);
        t += 16;
    }

#pragma unroll
    for (int u = 0; u < 4; ++u) step(pfB[u], false);

    // lane 63 finished (127,255) at t=507 -> c1
    if (lane == 63)
        out[b] = 1.0f / (1.0f + c1 * (1.0f / (float)(L1n + L2n)));
}

extern "C" void kernel_launch(void* const* d_in, const int* in_sizes, int n_in,
                              void* d_out, int out_size, void* d_ws, size_t ws_size,
                              hipStream_t stream) {
    const float* seq1 = (const float*)d_in[0];   // 64*128*1024 f32
    const float* seq2 = (const float*)d_in[1];   // 64*256*1024 f32
    float* out  = (float*)d_out;                 // 64 f32
    float* dist = (float*)d_ws;                  // 8 MB scratch (transposed dist)

    gemm_dist_kernel<<<dim3(512), dim3(256), 0, stream>>>(seq1, seq2, dist);
    dtw_kernel<<<dim3(64), dim3(64), 0, stream>>>(dist, out);
}